// Round 6
// baseline (259.266 us; speedup 1.0000x reference)
//
#include <hip/hip_runtime.h>
#include <cstdint>
#include <cstddef>

#define N_ 32
#define H_ 56
#define W_ 56
#define C_ 256
#define HP 58
#define WP 58

typedef int v4i  __attribute__((ext_vector_type(4)));
typedef int v16i __attribute__((ext_vector_type(16)));

// ---------------- kernel 1: weight sign bytes + |k| partial sums ------------
// wi8 layout: [tap][kc(8)][co(256)][32 ci bytes] -> linear in (tap,kc):
// bconv's B stream advances by exactly 8192 B per K-step (single voffset).
__global__ __launch_bounds__(256) void pack_w(const float* __restrict__ k,
                                              signed char* __restrict__ wi8,
                                              float* __restrict__ palpha) {
    int idx = blockIdx.x;
    int p = idx >> 2, q = idx & 3;       // tap, ci-quarter
    int co = threadIdx.x;
    float s = 0.f;
    #pragma unroll
    for (int half = 0; half < 2; ++half) {
        int kc = q * 2 + half;
        unsigned wrd[8];
        #pragma unroll
        for (int e = 0; e < 8; ++e) {
            unsigned wv = 0;
            #pragma unroll
            for (int j = 0; j < 4; ++j) {
                float v = k[(size_t)(p * 256 + kc * 32 + e * 4 + j) * 256 + co];
                s += fabsf(v);
                wv |= ((v > 0.f) ? 0x01u : 0xFFu) << (8 * j);
            }
            wrd[e] = wv;
        }
        v4i lo = {(int)wrd[0], (int)wrd[1], (int)wrd[2], (int)wrd[3]};
        v4i hi = {(int)wrd[4], (int)wrd[5], (int)wrd[6], (int)wrd[7]};
        size_t base = ((size_t)(p * 8 + kc) * 256 + co) * 2;
        ((v4i*)wi8)[base]     = lo;
        ((v4i*)wi8)[base + 1] = hi;
    }
    palpha[idx * 256 + co] = s;
}

// ---------------- kernel 2: fused pack + implicit-GEMM i8-MFMA conv ---------
// r5 PMC: MfmaUtil pinned at 22% across 3 loop structures = convoyed stalls on
// (a) 1-deep B prefetch (slack ~= period ~= L2 latency -> latency-bound
// equilibrium) and (b) compiler lgkmcnt(0) drain of plain A ds_reads.
// Fix: B = asm ring-4 issued 3 steps ahead (slot kc&3 static; tap*8 % 4 == 0),
// A = asm ds_read_b128 ring-2 issued 1 ahead; single counted wait
// "vmcnt(6) lgkmcnt(2)" + sched_barrier(0) (rule 18) + setprio around the
// MFMA quad (T5). Register budget: 32 B + 16 A + ~14 state + 64 acc <= 128.
__device__ __forceinline__ void epilogue(const v16i& acc, int mb, int svar,
                                         const float* bS, float alpha, float bv,
                                         int co, size_t obase,
                                         float* __restrict__ out) {
    #pragma unroll
    for (int r = 0; r < 16; ++r) {
        int row = (r & 3) + 8 * (r >> 2) + 4 * svar;   // verified 32x32 C/D map
        int m = mb + row;
        if (m < 112) {
            int hl = (m >= 56);
            int w = m - 56 * hl;
            float val = (float)acc[r] * (bS[m] * alpha) + bv;
            out[obase + ((size_t)hl * W_ + w) * C_ + co] = val;
        }
    }
}

__global__ __launch_bounds__(512, 4) void bconv(
        const float4* __restrict__ x4,
        const signed char* __restrict__ wi8, const float* __restrict__ palpha,
        const float* __restrict__ bias, float* __restrict__ out) {
    int bid = blockIdx.x;
    int bi = (bid & 7) * 112 + (bid >> 3);   // XCD swizzle (896 = 8*112, bijective)
    int n = bi / 28;
    int hb = (bi - n * 28) * 2;              // output rows hb, hb+1

    int tid = threadIdx.x;
    int lane = tid & 63, wid = tid >> 6;     // 8 waves
    int wm = wid >> 2, wn = wid & 3;
    int l31 = lane & 31, svar = lane >> 5;

    __shared__ __align__(16) signed char xs[4 * WP * 256];   // 59,392 B swizzled
    __shared__ float brow[4 * WP];
    __shared__ float bS[112];

    // ---- fused pack_x: binarize 4 padded rows into swizzled LDS + beta ----
    {
        int sl4 = lane >> 2;
        int bo  = (lane & 3) << 2;
        for (int i = 0; i < 29; ++i) {
            int pp = wid + 8 * i;            // 0..231
            int r = pp / WP, xc = pp - r * WP;
            int ypad = hb + r;
            bool inb = (ypad >= 1 && ypad <= H_ && xc >= 1 && xc <= W_);
            float4 v = make_float4(0.f, 0.f, 0.f, 0.f);
            if (inb)
                v = x4[(((size_t)n * H_ + (ypad - 1)) * W_ + (xc - 1)) * 64 + lane];
            unsigned wb = ((v.x > 0.f) ? 0x01u : 0xFFu)
                        | (((v.y > 0.f) ? 0x01u : 0xFFu) << 8)
                        | (((v.z > 0.f) ? 0x01u : 0xFFu) << 16)
                        | (((v.w > 0.f) ? 0x01u : 0xFFu) << 24);
            *(unsigned*)&xs[pp * 256 + ((sl4 ^ (pp & 15)) << 4) + bo] = wb;
            float s = fabsf(v.x) + fabsf(v.y) + fabsf(v.z) + fabsf(v.w);
            #pragma unroll
            for (int m = 32; m >= 1; m >>= 1) s += __shfl_xor(s, m, 64);
            if (lane == 0) brow[pp] = s * (1.f / 256.f);
        }
    }
    __syncthreads();

    // 3x3 window sums of beta (the avg_pool) for the 112 output pixels
    if (tid < 112) {
        int r = (tid >= 56);
        int w = tid - 56 * r;
        float s = 0.f;
        #pragma unroll
        for (int rr = 0; rr < 3; ++rr)
            #pragma unroll
            for (int d = 0; d < 3; ++d) s += brow[(r + rr) * WP + w + d];
        bS[tid] = s * (1.f / 9.f);
    }

    // per-lane pixel bases for this wave's two M-tiles (A row = lane&31)
    int m0 = wm * 64 + l31;                       // <= 95, always valid
    int m1 = m0 + 32;
    int m1e = m1 < 112 ? m1 : 111;                // pad lanes clamp, masked at store
    int hl0 = (m0 >= 56), hl1 = (m1e >= 56);
    int pb0 = hl0 * WP + (m0 - 56 * hl0);
    int pb1 = hl1 * WP + (m1e - 56 * hl1);

    int co0 = wn * 64 + l31;                      // B col = lane&31
    unsigned ldsb = (unsigned)(uintptr_t)&xs[0];

    v16i acc00 = {0,0,0,0,0,0,0,0,0,0,0,0,0,0,0,0};
    v16i acc01 = acc00, acc10 = acc00, acc11 = acc00;

    uint64_t wbase = (uint64_t)(uintptr_t)wi8;
    unsigned voff = (unsigned)(co0 * 2 + svar) * 16;   // +8192 per K-step

    // ---- B ring-4: preload steps 0..2 (3 ahead) ----
    v4i Bq0[4], Bq1[4];
    #pragma unroll
    for (int s = 0; s < 3; ++s) {
        asm volatile("global_load_dwordx4 %0, %2, %3\n\t"
                     "global_load_dwordx4 %1, %2, %3 offset:1024"
                     : "=&v"(Bq0[s]), "=&v"(Bq1[s]) : "v"(voff), "s"(wbase));
        voff += 8192;
    }

    // ---- A ring-2: preload step 0 (tap 0: kh=kw=0) ----
    unsigned t0 = ldsb + ((unsigned)pb0 << 8); int x0 = pb0 & 15;
    unsigned t1 = ldsb + ((unsigned)pb1 << 8); int x1 = pb1 & 15;
    v4i Aq0[2], Aq1[2];
    asm volatile("ds_read_b128 %0, %1" : "=&v"(Aq0[0]) : "v"(t0 + (unsigned)((svar ^ x0) << 4)));
    asm volatile("ds_read_b128 %0, %1" : "=&v"(Aq1[0]) : "v"(t1 + (unsigned)((svar ^ x1) << 4)));

    for (int tap = 0; tap < 9; ++tap) {
        #pragma unroll
        for (int kc = 0; kc < 8; ++kc) {
            // issue B(t+3) into static ring slot (kc+3)&3
            asm volatile("global_load_dwordx4 %0, %2, %3\n\t"
                         "global_load_dwordx4 %1, %2, %3 offset:1024"
                         : "=&v"(Bq0[(kc + 3) & 3]), "=&v"(Bq1[(kc + 3) & 3])
                         : "v"(voff), "s"(wbase));
            voff += 8192;
            // issue A(t+1) into ring slot (kc+1)&1
            if (kc < 7) {
                int sl = (kc + 1) * 2 + svar;
                asm volatile("ds_read_b128 %0, %1" : "=&v"(Aq0[(kc + 1) & 1])
                             : "v"(t0 + (unsigned)((sl ^ x0) << 4)));
                asm volatile("ds_read_b128 %0, %1" : "=&v"(Aq1[(kc + 1) & 1])
                             : "v"(t1 + (unsigned)((sl ^ x1) << 4)));
            } else {
                // next tap's (kc=0) fragments; tap 8 clamps to itself (dummy)
                int tn = (tap < 8) ? tap + 1 : 8;
                int khn = (tn * 11) >> 5, kwn = tn - khn * 3;
                int p0n = pb0 + khn * WP + kwn;
                int p1n = pb1 + khn * WP + kwn;
                unsigned t0n = ldsb + ((unsigned)p0n << 8);
                unsigned t1n = ldsb + ((unsigned)p1n << 8);
                asm volatile("ds_read_b128 %0, %1" : "=&v"(Aq0[0])
                             : "v"(t0n + (unsigned)((svar ^ (p0n & 15)) << 4)));
                asm volatile("ds_read_b128 %0, %1" : "=&v"(Aq1[0])
                             : "v"(t1n + (unsigned)((svar ^ (p1n & 15)) << 4)));
                // rotate tap bases for the next tap iteration
                t0 = t0n; x0 = p0n & 15;
                t1 = t1n; x1 = p1n & 15;
            }
            // B(t) done (6 newer B loads may fly); A(t) done (2 newer ds fly)
            asm volatile("s_waitcnt vmcnt(6) lgkmcnt(2)" ::: "memory");
            __builtin_amdgcn_sched_barrier(0);
            __builtin_amdgcn_s_setprio(1);
            acc00 = __builtin_amdgcn_mfma_i32_32x32x32_i8(Aq0[kc & 1], Bq0[kc & 3], acc00, 0, 0, 0);
            acc10 = __builtin_amdgcn_mfma_i32_32x32x32_i8(Aq1[kc & 1], Bq0[kc & 3], acc10, 0, 0, 0);
            acc01 = __builtin_amdgcn_mfma_i32_32x32x32_i8(Aq0[kc & 1], Bq1[kc & 3], acc01, 0, 0, 0);
            acc11 = __builtin_amdgcn_mfma_i32_32x32x32_i8(Aq1[kc & 1], Bq1[kc & 3], acc11, 0, 0, 0);
            __builtin_amdgcn_s_setprio(0);
        }
    }

    // drain dummy prefetches BEFORE their dest regs can be reused
    asm volatile("s_waitcnt vmcnt(0) lgkmcnt(0)" ::: "memory");
    __builtin_amdgcn_sched_barrier(0);

    __syncthreads();   // bS visible to all waves

    int co1 = co0 + 32;
    float a0s = 0.f, a1s = 0.f;
    for (int i = 0; i < 36; ++i) {
        a0s += palpha[i * 256 + co0];
        a1s += palpha[i * 256 + co1];
    }
    a0s *= (1.f / 2304.f);
    a1s *= (1.f / 2304.f);
    float bv0 = bias[co0], bv1 = bias[co1];

    size_t obase = (size_t)(n * H_ + hb) * W_ * C_;
    epilogue(acc00, wm * 64,      svar, bS, a0s, bv0, co0, obase, out);
    epilogue(acc01, wm * 64,      svar, bS, a1s, bv1, co1, obase, out);
    epilogue(acc10, wm * 64 + 32, svar, bS, a0s, bv0, co0, obase, out);
    epilogue(acc11, wm * 64 + 32, svar, bS, a1s, bv1, co1, obase, out);
}

extern "C" void kernel_launch(void* const* d_in, const int* in_sizes, int n_in,
                              void* d_out, int out_size, void* d_ws, size_t ws_size,
                              hipStream_t stream) {
    const float* x    = (const float*)d_in[0];
    const float* k    = (const float*)d_in[1];
    const float* bias = (const float*)d_in[2];
    float* out = (float*)d_out;

    char* ws = (char*)d_ws;
    signed char* wi8    = (signed char*)(ws);               // 589,824 B
    float*       palpha = (float*)(ws + 589824);            //  36,864 B
    // note: bconv's 3-deep tail dummy prefetches read up to ~623,616 B into
    // the workspace -- they land inside palpha (valid memory, values unused).

    pack_w<<<36, 256, 0, stream>>>(k, wi8, palpha);
    bconv<<<896, 512, 0, stream>>>((const float4*)x, wi8, palpha, bias, out);
}